// Round 1
// baseline (253.302 us; speedup 1.0000x reference)
//
#include <hip/hip_runtime.h>

// Integrator: y = cumsum(x, axis=-1) over (8,4,1048576) fp32.
// 3-phase scan-then-propagate:
//   phase1: per-tile sums (coalesced float4 reads)
//   phase2: exclusive scan of tile sums per row (tiny)
//   phase3: per-tile inclusive scan + tile offset, write out

constexpr int ROWS           = 32;        // B*C = 8*4
constexpr int T_LEN          = 1048576;   // time axis
constexpr int THREADS        = 256;
constexpr int PER_THREAD     = 16;        // contiguous floats per thread (phase 3)
constexpr int TILE           = THREADS * PER_THREAD;   // 4096 elems per block
constexpr int BLOCKS_PER_ROW = T_LEN / TILE;           // 256
constexpr int TOTAL_BLOCKS   = ROWS * BLOCKS_PER_ROW;  // 8192

// ---------------- phase 1: per-tile sums ----------------
__global__ __launch_bounds__(THREADS) void integ_phase1(
    const float* __restrict__ x, float* __restrict__ part) {
  const int blk  = blockIdx.x;                 // 0..TOTAL_BLOCKS-1
  const int row  = blk / BLOCKS_PER_ROW;
  const int tb   = blk % BLOCKS_PER_ROW;
  const size_t base = (size_t)row * T_LEN + (size_t)tb * TILE;
  const float4* p = (const float4*)(x + base);
  const int t = threadIdx.x;

  float s = 0.f;
  // coalesced: lane-contiguous float4 loads, 4 sweeps over the tile
#pragma unroll
  for (int j = 0; j < 4; ++j) {
    float4 v = p[j * THREADS + t];
    s += (v.x + v.y) + (v.z + v.w);
  }

  // wave reduce (64 lanes)
  const int lane = t & 63;
  const int wid  = t >> 6;
#pragma unroll
  for (int d = 32; d > 0; d >>= 1) s += __shfl_down(s, d, 64);

  __shared__ float wsum[4];
  if (lane == 0) wsum[wid] = s;
  __syncthreads();
  if (t == 0) part[blk] = (wsum[0] + wsum[1]) + (wsum[2] + wsum[3]);
}

// ---------------- phase 2: exclusive scan of tile sums, per row ----------------
__global__ __launch_bounds__(THREADS) void integ_phase2(float* __restrict__ part) {
  const int row = blockIdx.x;              // 0..ROWS-1
  const int t   = threadIdx.x;             // 0..255 == BLOCKS_PER_ROW-1
  const int idx = row * BLOCKS_PER_ROW + t;
  const float v = part[idx];

  // inclusive wave scan
  const int lane = t & 63;
  const int wid  = t >> 6;
  float s = v;
#pragma unroll
  for (int d = 1; d < 64; d <<= 1) {
    float n = __shfl_up(s, d, 64);
    if (lane >= d) s += n;
  }
  __shared__ float wsum[4];
  if (lane == 63) wsum[wid] = s;
  __syncthreads();
  float prev = 0.f;
#pragma unroll
  for (int w = 0; w < 4; ++w) prev += (w < wid) ? wsum[w] : 0.f;

  part[idx] = prev + s - v;   // exclusive prefix of this tile within the row
}

// ---------------- phase 3: local scan + offset, write ----------------
__global__ __launch_bounds__(THREADS) void integ_phase3(
    const float* __restrict__ x, float* __restrict__ y,
    const float* __restrict__ part) {
  const int blk  = blockIdx.x;
  const int row  = blk / BLOCKS_PER_ROW;
  const int tb   = blk % BLOCKS_PER_ROW;
  const size_t base = (size_t)row * T_LEN + (size_t)tb * TILE;
  const int t = threadIdx.x;

  // each thread owns PER_THREAD contiguous floats
  const float4* p = (const float4*)(x + base + (size_t)t * PER_THREAD);
  float v[PER_THREAD];
#pragma unroll
  for (int j = 0; j < PER_THREAD / 4; ++j) {
    float4 q = p[j];
    v[4 * j + 0] = q.x; v[4 * j + 1] = q.y; v[4 * j + 2] = q.z; v[4 * j + 3] = q.w;
  }

  // thread-local inclusive scan
#pragma unroll
  for (int i = 1; i < PER_THREAD; ++i) v[i] += v[i - 1];
  const float tsum = v[PER_THREAD - 1];

  // block exclusive scan of per-thread sums
  const int lane = t & 63;
  const int wid  = t >> 6;
  float s = tsum;
#pragma unroll
  for (int d = 1; d < 64; d <<= 1) {
    float n = __shfl_up(s, d, 64);
    if (lane >= d) s += n;
  }
  __shared__ float wsum[4];
  if (lane == 63) wsum[wid] = s;
  __syncthreads();
  float prev = 0.f;
#pragma unroll
  for (int w = 0; w < 4; ++w) prev += (w < wid) ? wsum[w] : 0.f;
  const float ex = prev + s - tsum;         // exclusive prefix within tile

  const float off = part[blk] + ex;         // tile offset + within-tile offset
#pragma unroll
  for (int i = 0; i < PER_THREAD; ++i) v[i] += off;

  float4* q = (float4*)(y + base + (size_t)t * PER_THREAD);
#pragma unroll
  for (int j = 0; j < PER_THREAD / 4; ++j) {
    float4 o;
    o.x = v[4 * j + 0]; o.y = v[4 * j + 1]; o.z = v[4 * j + 2]; o.w = v[4 * j + 3];
    q[j] = o;
  }
}

extern "C" void kernel_launch(void* const* d_in, const int* in_sizes, int n_in,
                              void* d_out, int out_size, void* d_ws, size_t ws_size,
                              hipStream_t stream) {
  const float* x = (const float*)d_in[0];
  float* y = (float*)d_out;
  float* part = (float*)d_ws;   // TOTAL_BLOCKS floats = 32 KB

  integ_phase1<<<TOTAL_BLOCKS, THREADS, 0, stream>>>(x, part);
  integ_phase2<<<ROWS, THREADS, 0, stream>>>(part);
  integ_phase3<<<TOTAL_BLOCKS, THREADS, 0, stream>>>(x, y, part);
}